// Round 8
// baseline (216.153 us; speedup 1.0000x reference)
//
#include <hip/hip_runtime.h>
#include <hip/hip_bf16.h>

#define NTOK 1024     // tokens
#define TKN  2048     // expanded tokens (NTOK * topk)
#define NE   8        // experts
#define NRANK 4
#define IPR  1024     // intermediate per rank
#define HD   2048     // hidden
#define KD   4096     // NRANK * IPR
#define BM   256
#define BN   128
#define BK   64
#define KSPLIT 2
#define KPS  (KD / KSPLIT)   // 2048 K per split
#define NIT  (KPS / BK)      // 32 k-iterations per block
#define XS   72              // LDS row stride in elements (144 B rows)
#define MAXTILES 16          // worst case sum ceil(c_e/256) <= 15
#define NBL  (HD / BN)       // 16 n-blocks
#define NWG  (MAXTILES * NBL * KSPLIT)  // 512 blocks, % 8 == 0

#define WS_YEXP_OFF 32768
#define WS_NEED ((size_t)WS_YEXP_OFF + (size_t)KSPLIT * TKN * HD * 4)

typedef __bf16 bf16x8 __attribute__((ext_vector_type(8)));
typedef float f32x4 __attribute__((ext_vector_type(4)));
typedef unsigned short u16x8 __attribute__((ext_vector_type(8)));

static __device__ inline unsigned short f2b(float f) {
  return __builtin_bit_cast(unsigned short, __float2bfloat16(f));
}

// ---------------- zero d_out (fallback path only) ----------------
__global__ __launch_bounds__(256) void zero_kernel(float* __restrict__ p) {
  size_t i = ((size_t)blockIdx.x * 256 + threadIdx.x) * 4;
  *reinterpret_cast<float4*>(p + i) = float4{0.f, 0.f, 0.f, 0.f};
}

// ---------------- routing: top-2 + softmax gates + expert grouping ----------------
__global__ void routing_kernel(const float* __restrict__ logits,
                               float* __restrict__ gate,
                               int* __restrict__ perm,
                               int* __restrict__ tile_e,
                               int* __restrict__ tile_r0,
                               int* __restrict__ tile_nr) {
  __shared__ int cnt[NE];
  __shared__ int cur[NE];
  const int tid = threadIdx.x;   // one thread per token, 1024 threads
  if (tid < NE) cnt[tid] = 0;
  __syncthreads();

  float l[NE];
#pragma unroll
  for (int e = 0; e < NE; ++e) l[e] = logits[tid * NE + e];

  float v0 = l[0]; int i0 = 0;
  float v1 = -3.4e38f; int i1 = 0;
#pragma unroll
  for (int e = 1; e < NE; ++e) {
    if (l[e] > v0) { v1 = v0; i1 = i0; v0 = l[e]; i0 = e; }
    else if (l[e] > v1) { v1 = l[e]; i1 = e; }
  }
  float e1  = expf(v1 - v0);      // v1 <= v0
  float inv = 1.0f / (1.0f + e1);
  gate[2 * tid]     = inv;        // slot 0 = argmax
  gate[2 * tid + 1] = e1 * inv;   // slot 1

  atomicAdd(&cnt[i0], 1);
  atomicAdd(&cnt[i1], 1);
  __syncthreads();

  if (tid == 0) {
    int run = 0, nt = 0;
    for (int e = 0; e < NE; ++e) {
      cur[e] = run;
      int c = cnt[e];
      for (int r0 = 0; r0 < c; r0 += BM) {
        tile_e[nt]  = e;
        tile_r0[nt] = run + r0;
        tile_nr[nt] = (c - r0 < BM) ? (c - r0) : BM;
        ++nt;
      }
      run += c;
    }
    for (; nt < MAXTILES; ++nt) tile_e[nt] = -1;
  }
  __syncthreads();

  int p0 = atomicAdd(&cur[i0], 1); perm[p0] = 2 * tid;
  int p1 = atomicAdd(&cur[i1], 1); perm[p1] = 2 * tid + 1;
}

// ---------------- grouped GEMM (K-split=2), 512 thr = 8 waves (4M x 2N) ----------------
// WSP=1: plain stores of raw partials to yexp[ksp][tk][h] (no atomics, gate in combine).
// WSP=0: fallback atomicAdd path into out (gate applied here).
template <int WSP>
__global__ __launch_bounds__(512, 4) void gemm_kernel(
    const float* __restrict__ x,   // f32 [NRANK][TKN][IPR]
    const float* __restrict__ w,   // f32 [NRANK][NE][IPR][HD]
    const int* __restrict__ perm,
    const int* __restrict__ tile_e,
    const int* __restrict__ tile_r0,
    const int* __restrict__ tile_nr,
    const float* __restrict__ gate,
    float* __restrict__ yexp,
    float* __restrict__ out) {
  // Balanced swizzle: chunk of 64 consecutive sw per XCD; tile is the FASTEST
  // axis so data-dependent empty tiles spread evenly over XCDs.
  const int id = blockIdx.x;
  const int sw = (id & 7) * (NWG / 8) + (id >> 3);
  const int tile = sw & (MAXTILES - 1);
  const int nb   = (sw >> 4) & (NBL - 1);
  const int ksp  = sw >> 8;

  const int e = tile_e[tile];
  if (e < 0) return;
  const int row0 = tile_r0[tile];
  const int nr   = tile_nr[tile];
  const int n0   = nb * BN;
  const int kbase = ksp * KPS;

  __shared__ unsigned short Xs[BM][XS];   // bf16 bits, [m][k]  (36 KB)
  __shared__ unsigned short Ws[BN][XS];   // bf16 bits, transposed: [n][k] (18 KB)

  const int tid  = threadIdx.x;
  const int lane = tid & 63;
  const int wid  = tid >> 6;   // 0..7
  const int wr   = wid >> 1;   // 0..3 : 64-row stripe
  const int wc   = wid & 1;    // 0..1 : 64-col stripe

  // ---- X staging coords: 4 passes; 8 threads per row, 32 B (8 f32) each ----
  const int xr = tid >> 3;          // 0..63 (row within pass)
  const int xc = (tid & 7) << 3;    // k-offset 0,8,...,56
  int xtk[4];
#pragma unroll
  for (int p = 0; p < 4; ++p) {
    const int row = p * 64 + xr;
    xtk[p] = (row < nr) ? perm[row0 + row] : -1;
  }

  // ---- W staging coords: one n-column per thread, 16 k-values ----
  const int wn  = tid & 127;         // n within tile (consecutive lanes -> consecutive n)
  const int wkg = (tid >> 7) << 4;   // 0,16,32,48 (k-quarter)

  // prefetch registers (packed to bf16 immediately -> lower VGPR pressure)
  u16x8 xpk[4];
  u16x8 wpk[2];

#define LOADREGS(KT) do {                                                        \
    const int r_  = (KT) >> 10;                                                  \
    const int i0_ = (KT) & 1023;                                                 \
    _Pragma("unroll")                                                            \
    for (int p_ = 0; p_ < 4; ++p_) {                                             \
      if (xtk[p_] >= 0) {                                                        \
        const float* sp_ = x + ((size_t)r_ * TKN + xtk[p_]) * IPR + i0_ + xc;    \
        float4 f0_ = *reinterpret_cast<const float4*>(sp_);                      \
        float4 f1_ = *reinterpret_cast<const float4*>(sp_ + 4);                  \
        u16x8 v_;                                                                \
        v_[0] = f2b(f0_.x); v_[1] = f2b(f0_.y); v_[2] = f2b(f0_.z);              \
        v_[3] = f2b(f0_.w); v_[4] = f2b(f1_.x); v_[5] = f2b(f1_.y);              \
        v_[6] = f2b(f1_.z); v_[7] = f2b(f1_.w);                                  \
        xpk[p_] = v_;                                                            \
      } else {                                                                   \
        xpk[p_] = u16x8{0, 0, 0, 0, 0, 0, 0, 0};                                 \
      }                                                                          \
    }                                                                            \
    const float* wp_ = w + (((size_t)r_ * NE + e) * IPR + i0_ + wkg) * HD + n0 + wn; \
    _Pragma("unroll")                                                            \
    for (int h_ = 0; h_ < 2; ++h_) {                                             \
      float t0_ = wp_[(size_t)(h_ * 8 + 0) * HD];                                \
      float t1_ = wp_[(size_t)(h_ * 8 + 1) * HD];                                \
      float t2_ = wp_[(size_t)(h_ * 8 + 2) * HD];                                \
      float t3_ = wp_[(size_t)(h_ * 8 + 3) * HD];                                \
      float t4_ = wp_[(size_t)(h_ * 8 + 4) * HD];                                \
      float t5_ = wp_[(size_t)(h_ * 8 + 5) * HD];                                \
      float t6_ = wp_[(size_t)(h_ * 8 + 6) * HD];                                \
      float t7_ = wp_[(size_t)(h_ * 8 + 7) * HD];                                \
      u16x8 v_;                                                                  \
      v_[0] = f2b(t0_); v_[1] = f2b(t1_); v_[2] = f2b(t2_); v_[3] = f2b(t3_);    \
      v_[4] = f2b(t4_); v_[5] = f2b(t5_); v_[6] = f2b(t6_); v_[7] = f2b(t7_);    \
      wpk[h_] = v_;                                                              \
    }                                                                            \
  } while (0)

  f32x4 acc[4][4];
#pragma unroll
  for (int a = 0; a < 4; ++a)
#pragma unroll
    for (int b = 0; b < 4; ++b) acc[a][b] = f32x4{0.f, 0.f, 0.f, 0.f};

  const int lrow = lane & 15;
  const int lk   = (lane >> 4) << 3;   // 0,8,16,24

  LOADREGS(kbase);

  for (int t = 0; t < NIT; ++t) {
    __syncthreads();   // previous compute done; LDS free

    // ---- write prefetched (already bf16-packed) regs -> LDS ----
#pragma unroll
    for (int p = 0; p < 4; ++p)
      *reinterpret_cast<u16x8*>(&Xs[p * 64 + xr][xc]) = xpk[p];
    *reinterpret_cast<u16x8*>(&Ws[wn][wkg])     = wpk[0];
    *reinterpret_cast<u16x8*>(&Ws[wn][wkg + 8]) = wpk[1];
    __syncthreads();   // LDS ready

    // ---- prefetch next iteration (overlaps compute below) ----
    if (t + 1 < NIT) LOADREGS(kbase + (t + 1) * BK);

    // ---- compute: 2 k-steps of 32, 4x4 fragments per wave ----
#pragma unroll
    for (int ks = 0; ks < 2; ++ks) {
      bf16x8 af[4], bfr[4];
#pragma unroll
      for (int mi = 0; mi < 4; ++mi)
        af[mi] = __builtin_bit_cast(bf16x8,
            *reinterpret_cast<const u16x8*>(&Xs[wr * 64 + mi * 16 + lrow][ks * 32 + lk]));
#pragma unroll
      for (int ni = 0; ni < 4; ++ni)
        bfr[ni] = __builtin_bit_cast(bf16x8,
            *reinterpret_cast<const u16x8*>(&Ws[wc * 64 + ni * 16 + lrow][ks * 32 + lk]));
#pragma unroll
      for (int mi = 0; mi < 4; ++mi)
#pragma unroll
        for (int ni = 0; ni < 4; ++ni)
          acc[mi][ni] = __builtin_amdgcn_mfma_f32_16x16x32_bf16(af[mi], bfr[ni], acc[mi][ni], 0, 0, 0);
    }
  }

  // ---- epilogue ----
  const int mb = (lane >> 4) << 2;
#pragma unroll
  for (int mi = 0; mi < 4; ++mi) {
#pragma unroll
    for (int q = 0; q < 4; ++q) {
      const int m = wr * 64 + mi * 16 + mb + q;
      if (m < nr) {
        const int tk = perm[row0 + m];
        if (WSP) {
          // raw partial, plain stores (gate applied in combine)
          float* dst = yexp + ((size_t)ksp * TKN + tk) * HD + n0 + wc * 64 + lrow;
#pragma unroll
          for (int ni = 0; ni < 4; ++ni)
            dst[ni * 16] = acc[mi][ni][q];
        } else {
          const float g = gate[tk];
          float* dst = out + (size_t)(tk >> 1) * HD + n0 + wc * 64 + lrow;
#pragma unroll
          for (int ni = 0; ni < 4; ++ni)
            atomicAdd(&dst[ni * 16], g * acc[mi][ni][q]);
        }
      }
    }
  }
#undef LOADREGS
}

// ---------------- combine: out[t][h] = sum_s gate[2t+s] * sum_ksp yexp[ksp][2t+s][h] ----------------
__global__ __launch_bounds__(256) void combine_kernel(const float* __restrict__ yexp,
                                                      const float* __restrict__ gate,
                                                      float* __restrict__ out) {
  const int idx = blockIdx.x * 256 + threadIdx.x;  // 0 .. NTOK*HD/4-1
  const int t  = idx >> 9;            // HD/4 = 512 chunks per token
  const int h4 = (idx & 511) << 2;
  const float g0 = gate[2 * t];
  const float g1 = gate[2 * t + 1];

  const float* y00 = yexp + ((size_t)(2 * t)) * HD + h4;              // ksp0 slot0
  const float* y01 = yexp + ((size_t)(2 * t + 1)) * HD + h4;          // ksp0 slot1
  const float* y10 = yexp + ((size_t)TKN + 2 * t) * HD + h4;          // ksp1 slot0
  const float* y11 = yexp + ((size_t)TKN + 2 * t + 1) * HD + h4;      // ksp1 slot1
  float4 a0 = *reinterpret_cast<const float4*>(y00);
  float4 a1 = *reinterpret_cast<const float4*>(y01);
  float4 b0 = *reinterpret_cast<const float4*>(y10);
  float4 b1 = *reinterpret_cast<const float4*>(y11);

  float4 o;
  o.x = g0 * (a0.x + b0.x) + g1 * (a1.x + b1.x);
  o.y = g0 * (a0.y + b0.y) + g1 * (a1.y + b1.y);
  o.z = g0 * (a0.z + b0.z) + g1 * (a1.z + b1.z);
  o.w = g0 * (a0.w + b0.w) + g1 * (a1.w + b1.w);
  *reinterpret_cast<float4*>(out + (size_t)t * HD + h4) = o;
}

extern "C" void kernel_launch(void* const* d_in, const int* in_sizes, int n_in,
                              void* d_out, int out_size, void* d_ws, size_t ws_size,
                              hipStream_t stream) {
  const float* x      = (const float*)d_in[0];  // f32 (upcast from fp16)
  const float* w      = (const float*)d_in[1];  // f32 (upcast from fp16)
  const float* logits = (const float*)d_in[2];
  // d_in[3] = topk (constant 2), unused

  char* ws = (char*)d_ws;
  float* gate    = (float*)(ws + 0);          // TKN floats   (8 KB)
  int*   perm    = (int*)(ws + 8192);         // TKN ints     (8 KB)
  int*   tile_e  = (int*)(ws + 16384);        // MAXTILES ints
  int*   tile_r0 = (int*)(ws + 16384 + 256);
  int*   tile_nr = (int*)(ws + 16384 + 512);
  float* yexp    = (float*)(ws + WS_YEXP_OFF); // [KSPLIT][TKN][HD] f32 (33.6 MB)

  float* outf = (float*)d_out;                // f32 output [NTOK][HD]

  routing_kernel<<<1, 1024, 0, stream>>>(logits, gate, perm, tile_e, tile_r0, tile_nr);

  if (ws_size >= WS_NEED) {
    // no-atomic path: plain stores to yexp, then gated combine (deterministic)
    gemm_kernel<1><<<NWG, 512, 0, stream>>>(x, w, perm, tile_e, tile_r0, tile_nr,
                                            gate, yexp, outf);
    combine_kernel<<<(NTOK * HD / 4) / 256, 256, 0, stream>>>(yexp, gate, outf);
  } else {
    // fallback: atomic accumulation directly into out
    zero_kernel<<<(NTOK * HD / 4) / 256, 256, 0, stream>>>(outf);
    gemm_kernel<0><<<NWG, 512, 0, stream>>>(x, w, perm, tile_e, tile_r0, tile_nr,
                                            gate, yexp, outf);
  }
}